// Round 7
// baseline (534.598 us; speedup 1.0000x reference)
//
#include <hip/hip_runtime.h>
#include <hip/hip_bf16.h>

// Problem constants
constexpr int B = 4, L = 2048, E = 300, D = 128, NH = 4, HD = 128, NL = 3, D2 = 512;
constexpr int L1 = L + 1; // 2049
constexpr float EPS = 1e-5f;
constexpr float SCALE = 0.08838834764831843f; // 1/sqrt(128)
constexpr int NCH = 32;              // relay-attention L-chunks
constexpr int CHUNK = 65;            // ceil(2049/32)

typedef unsigned int uint_t;
typedef unsigned short u16;
typedef short bf16x8 __attribute__((ext_vector_type(8)));
typedef float f32x4 __attribute__((ext_vector_type(4)));

__device__ __forceinline__ u16 f2bf(float f) {
  union { float f; uint_t i; } x; x.f = f;
  uint_t r = x.i + 0x7fffu + ((x.i >> 16) & 1u);
  return (u16)(r >> 16);
}
__device__ __forceinline__ uint_t packbf(float a, float b) {
  return (uint_t)f2bf(a) | ((uint_t)f2bf(b) << 16);
}
__device__ __forceinline__ float bf2f(u16 u) {
  union { uint_t i; float f; } x; x.i = ((uint_t)u) << 16; return x.f;
}
__device__ __forceinline__ float2 bf2x2(uint_t u) {
  union { uint_t i; float f; } a, b;
  a.i = (u & 0xffffu) << 16; b.i = u & 0xffff0000u;
  return make_float2(a.f, b.f);
}

// ---------------- weight pre-conversion: 4 tensors (rq,rk,rv,ro), NL*D*D2 fp32 -> bf16
struct WCArgs { const float* s[4]; u16* d[4]; };
__global__ __launch_bounds__(256) void wconv(WCArgs wa) {
  int ti = blockIdx.y;
  const float* s = wa.s[ti]; u16* dd = wa.d[ti];
  int i = (blockIdx.x * 256 + threadIdx.x) * 4;
  float4 f = *(const float4*)(s + i);
  *(uint2*)(dd + i) = make_uint2(packbf(f.x, f.y), packbf(f.z, f.w));
}

// ================= all-bf16 MFMA GEMM, BK=128: out[M,N] = A[M,K] @ W[N,K]^T + bias
// 64x64 tile, 256 threads = 4 waves 2x2 (each 32x32).
struct GDesc {
  const u16* A; const u16* W; const float* bias;
  u16* outb;                // bf16 output (when !residleaky)
  float* outf;              // fp32 output (residleaky path)
  const float* resid; u16* out2b; const int* mask;
  int residleaky;
};
struct GArgs { GDesc d[5]; };

__global__ __launch_bounds__(256) void gemm_bf(GArgs ga, int nby, int N, int K) {
  __shared__ u16 As[64][136];
  __shared__ u16 Ws[64][136];
  int t = threadIdx.x;
  int bm = blockIdx.x;
  int di = blockIdx.y / nby, bn = blockIdx.y - di * nby;
  GDesc d = ga.d[di];
  const int rowA = bm * 64, rowW = bn * 64;

  f32x4 acc[2][2];
#pragma unroll
  for (int i = 0; i < 2; i++)
#pragma unroll
    for (int j = 0; j < 2; j++)
      acc[i][j] = (f32x4){0.f, 0.f, 0.f, 0.f};

  const int r = t >> 2;             // 0..63
  const int c0 = (t & 3) * 32;      // 0,32,64,96 (shorts)
  const int wid = t >> 6;
  const int wm = (wid & 1) * 32, wn = (wid >> 1) * 32;
  const int lr = t & 15, quad = (t >> 4) & 3;

  const u16* Arow = d.A + (size_t)(rowA + r) * K;
  const u16* Wrow = d.W + (size_t)(rowW + r) * K;

  for (int kt = 0; kt < K; kt += 128) {
    uint4 a0 = *(const uint4*)(Arow + kt + c0);
    uint4 a1 = *(const uint4*)(Arow + kt + c0 + 8);
    uint4 a2 = *(const uint4*)(Arow + kt + c0 + 16);
    uint4 a3 = *(const uint4*)(Arow + kt + c0 + 24);
    uint4 w0 = *(const uint4*)(Wrow + kt + c0);
    uint4 w1 = *(const uint4*)(Wrow + kt + c0 + 8);
    uint4 w2 = *(const uint4*)(Wrow + kt + c0 + 16);
    uint4 w3 = *(const uint4*)(Wrow + kt + c0 + 24);
    __syncthreads();
    *(uint4*)&As[r][c0] = a0; *(uint4*)&As[r][c0 + 8] = a1;
    *(uint4*)&As[r][c0 + 16] = a2; *(uint4*)&As[r][c0 + 24] = a3;
    *(uint4*)&Ws[r][c0] = w0; *(uint4*)&Ws[r][c0 + 8] = w1;
    *(uint4*)&Ws[r][c0 + 16] = w2; *(uint4*)&Ws[r][c0 + 24] = w3;
    __syncthreads();
#pragma unroll
    for (int ks = 0; ks < 4; ks++) {
      bf16x8 af[2], bfr[2];
#pragma unroll
      for (int mt = 0; mt < 2; mt++)
        af[mt] = *(const bf16x8*)&As[wm + mt * 16 + lr][ks * 32 + quad * 8];
#pragma unroll
      for (int nt = 0; nt < 2; nt++)
        bfr[nt] = *(const bf16x8*)&Ws[wn + nt * 16 + lr][ks * 32 + quad * 8];
#pragma unroll
      for (int mt = 0; mt < 2; mt++)
#pragma unroll
        for (int nt = 0; nt < 2; nt++)
          acc[mt][nt] = __builtin_amdgcn_mfma_f32_16x16x32_bf16(af[mt], bfr[nt], acc[mt][nt], 0, 0, 0);
    }
  }

  // epilogue: C/D layout col=lane&15, row=quad*4+reg
#pragma unroll
  for (int nt = 0; nt < 2; nt++) {
    int col = rowW + wn + nt * 16 + lr;
    float bv = d.bias[col];
#pragma unroll
    for (int mt = 0; mt < 2; mt++) {
#pragma unroll
      for (int rr = 0; rr < 4; rr++) {
        int row = rowA + wm + mt * 16 + quad * 4 + rr;
        float v = acc[mt][nt][rr] + bv;
        if (d.residleaky) {
          v = (v > 0.f) ? v : 0.01f * v;
          v += d.resid[(size_t)row * N + col];
          if (d.mask[row] == 0) v = 0.f;
          d.outf[(size_t)row * N + col] = v;
          d.out2b[(size_t)row * N + col] = f2bf(v);
        } else {
          d.outb[(size_t)row * N + col] = f2bf(v);
        }
      }
    }
  }
}

// ================= fp32-input MFMA GEMM for the embedding projection (gathered A, K=300)
__global__ __launch_bounds__(256) void gemm_embed(
    const float* __restrict__ A, const float* __restrict__ W, const float* __restrict__ bias,
    float* __restrict__ outf, u16* __restrict__ outb,
    const int* __restrict__ gather, int N, int K) {
  __shared__ u16 As[64][72];
  __shared__ u16 Ws[64][72];
  int t = threadIdx.x;
  int bm = blockIdx.x, bn = blockIdx.y;
  const int rowA = bm * 64, rowW = bn * 64;

  f32x4 acc[2][2];
#pragma unroll
  for (int i = 0; i < 2; i++)
#pragma unroll
    for (int j = 0; j < 2; j++)
      acc[i][j] = (f32x4){0.f, 0.f, 0.f, 0.f};

  const int srow = t >> 2, sc0 = (t & 3) * 16;
  const int wid = t >> 6, wm = (wid & 1) * 32, wn = (wid >> 1) * 32;
  const int lr = t & 15, quad = (t >> 4) & 3;

  const float* Arow = A + (size_t)gather[rowA + srow] * K;
  const float* Wrow = W + (size_t)(rowW + srow) * K;

  for (int kt = 0; kt < K; kt += 64) {
    __syncthreads();
    bool full = (kt + 64 <= K);
#pragma unroll
    for (int ch = 0; ch < 4; ch++) {
      int c = kt + sc0 + ch * 4;
      float4 fa, fw;
      if (full) {
        fa = *(const float4*)(Arow + c);
        fw = *(const float4*)(Wrow + c);
      } else {
        fa.x = (c + 0 < K) ? Arow[c + 0] : 0.f;
        fa.y = (c + 1 < K) ? Arow[c + 1] : 0.f;
        fa.z = (c + 2 < K) ? Arow[c + 2] : 0.f;
        fa.w = (c + 3 < K) ? Arow[c + 3] : 0.f;
        fw.x = (c + 0 < K) ? Wrow[c + 0] : 0.f;
        fw.y = (c + 1 < K) ? Wrow[c + 1] : 0.f;
        fw.z = (c + 2 < K) ? Wrow[c + 2] : 0.f;
        fw.w = (c + 3 < K) ? Wrow[c + 3] : 0.f;
      }
      *(uint2*)&As[srow][sc0 + ch * 4] = make_uint2(packbf(fa.x, fa.y), packbf(fa.z, fa.w));
      *(uint2*)&Ws[srow][sc0 + ch * 4] = make_uint2(packbf(fw.x, fw.y), packbf(fw.z, fw.w));
    }
    __syncthreads();
#pragma unroll
    for (int ks = 0; ks < 2; ks++) {
      bf16x8 af[2], bfr[2];
#pragma unroll
      for (int mt = 0; mt < 2; mt++)
        af[mt] = *(const bf16x8*)&As[wm + mt * 16 + lr][ks * 32 + quad * 8];
#pragma unroll
      for (int nt = 0; nt < 2; nt++)
        bfr[nt] = *(const bf16x8*)&Ws[wn + nt * 16 + lr][ks * 32 + quad * 8];
#pragma unroll
      for (int mt = 0; mt < 2; mt++)
#pragma unroll
        for (int nt = 0; nt < 2; nt++)
          acc[mt][nt] = __builtin_amdgcn_mfma_f32_16x16x32_bf16(af[mt], bfr[nt], acc[mt][nt], 0, 0, 0);
    }
  }
#pragma unroll
  for (int nt = 0; nt < 2; nt++) {
    int col = rowW + wn + nt * 16 + lr;
    float bv = bias[col];
#pragma unroll
    for (int mt = 0; mt < 2; mt++) {
#pragma unroll
      for (int rr = 0; rr < 4; rr++) {
        int row = rowA + wm + mt * 16 + quad * 4 + rr;
        float v = acc[mt][nt][rr] + bv;
        outf[(size_t)row * N + col] = v;       // nodes (fp32)
        outb[(size_t)row * N + col] = f2bf(v); // xb (bf16)
      }
    }
  }
}

// ---------------- relay = mean over L of nodes  (relay zeroed first)
__global__ __launch_bounds__(128) void relay_init_kernel(const float* __restrict__ x, float* __restrict__ relay) {
  int b = blockIdx.x >> 6, c = blockIdx.x & 63, t = threadIdx.x;
  float sum = 0.f;
  for (int i = 0; i < 32; i++) {
    int l = c * 32 + i;
    sum += x[((size_t)b * L + l) * D + t];
  }
  atomicAdd(&relay[b * D + t], sum * (1.0f / L));
}

// ---------------- layernorm (fp32 in, bf16 out)
__global__ __launch_bounds__(128) void ln_kernel(
    const float* __restrict__ in, u16* __restrict__ out,
    const float* __restrict__ g, const float* __restrict__ bb) {
  int row = blockIdx.x, t = threadIdx.x;
  float v = in[(size_t)row * D + t];
  float s = v, s2 = v * v;
#pragma unroll
  for (int o = 1; o < 64; o <<= 1) { s += __shfl_xor(s, o, 64); s2 += __shfl_xor(s2, o, 64); }
  __shared__ float rs[2], rs2[2];
  int w = t >> 6;
  if ((t & 63) == 0) { rs[w] = s; rs2[w] = s2; }
  __syncthreads();
  float S = rs[0] + rs[1], S2 = rs2[0] + rs2[1];
  float mu = S * (1.0f / D);
  float var = S2 * (1.0f / D) - mu * mu;
  float r = rsqrtf(var + EPS);
  out[(size_t)row * D + t] = f2bf((v - mu) * r * g[t] + bb[t]);
}

// ---------------- per-layer relay-side projections: rk/rv (for ring), u = SCALE*(sq@sk_w), c
__global__ __launch_bounds__(256) void relay_step(
    const float* __restrict__ relay,
    const float* __restrict__ rkw, const float* __restrict__ rkb,
    const float* __restrict__ rvw, const float* __restrict__ rvb,
    const float* __restrict__ sqw, const float* __restrict__ sqb,
    const float* __restrict__ skw, const float* __restrict__ skb_,
    float* __restrict__ relay_k, float* __restrict__ relay_v,
    float* __restrict__ u, float* __restrict__ cvec) {
  int b = blockIdx.x, t = threadIdx.x;
  __shared__ float rel[D];
  __shared__ float sql[D2];
  if (t < D) rel[t] = relay[(size_t)b * D + t];
  __syncthreads();
#pragma unroll
  for (int rep = 0; rep < 2; rep++) {
    int n = rep * 256 + t;
    float a1 = rkb[n], a2 = rvb[n], a3 = sqb[n];
    const float4* w1 = (const float4*)(rkw + (size_t)n * D);
    const float4* w2 = (const float4*)(rvw + (size_t)n * D);
    const float4* w3 = (const float4*)(sqw + (size_t)n * D);
    const float4* rl = (const float4*)rel;
#pragma unroll 8
    for (int d = 0; d < D / 4; d++) {
      float4 rv4 = rl[d], x1 = w1[d], x2 = w2[d], x3 = w3[d];
      a1 += rv4.x * x1.x + rv4.y * x1.y + rv4.z * x1.z + rv4.w * x1.w;
      a2 += rv4.x * x2.x + rv4.y * x2.y + rv4.z * x2.z + rv4.w * x2.w;
      a3 += rv4.x * x3.x + rv4.y * x3.y + rv4.z * x3.z + rv4.w * x3.w;
    }
    relay_k[(size_t)b * D2 + n] = a1;
    relay_v[(size_t)b * D2 + n] = a2;
    sql[n] = a3;
  }
  __syncthreads();
#pragma unroll
  for (int rep = 0; rep < 2; rep++) {
    int idx = rep * 256 + t;
    int n = idx >> 7, dd = idx & 127;
    float acc = 0.f;
    const float* wp = skw + (size_t)(n * HD) * D + dd;
    for (int h = 0; h < HD; h++) acc += sql[n * HD + h] * wp[(size_t)h * D];
    u[((size_t)b * NH + n) * D + dd] = acc * SCALE;
  }
  if (t < NH) {
    float acc = 0.f;
    for (int h = 0; h < HD; h++) acc += sql[t * HD + h] * skb_[t * HD + h];
    cvec[b * NH + t] = acc * SCALE;
  }
}

// ---------------- ring (windowed) attention; bf16 q/k/v/ak/av + att, fp32 rk/rv
__global__ __launch_bounds__(256) void ring_attn_kernel(
    const u16* __restrict__ q, const u16* __restrict__ k, const u16* __restrict__ v,
    const u16* __restrict__ akr, const u16* __restrict__ avr,
    const float* __restrict__ rk, const float* __restrict__ rv,
    u16* __restrict__ att) {
  int bl = blockIdx.x;
  int b = bl >> 11, l = bl & (L - 1);
  int n = threadIdx.x >> 6, lane = threadIdx.x & 63;
  int h = lane << 1;
  size_t base = (size_t)bl * D2 + n * HD + h;
  float2 qv = bf2x2(*(const uint_t*)(q + base));
  float s[5], v0[5], v1[5];
#pragma unroll
  for (int u = 0; u < 5; u++) {
    float k0 = 0.f, k1 = 0.f, vv0 = 0.f, vv1 = 0.f;
    if (u < 3) {
      int ll = l + u - 1;
      if (ll >= 0 && ll < L) {
        size_t off = ((size_t)b * L + ll) * D2 + n * HD + h;
        float2 kf = bf2x2(*(const uint_t*)(k + off));
        float2 vf = bf2x2(*(const uint_t*)(v + off));
        k0 = kf.x; k1 = kf.y; vv0 = vf.x; vv1 = vf.y;
      }
    } else if (u == 3) {
      float2 kf = bf2x2(*(const uint_t*)(akr + base));
      float2 vf = bf2x2(*(const uint_t*)(avr + base));
      k0 = kf.x; k1 = kf.y; vv0 = vf.x; vv1 = vf.y;
    } else {
      size_t rb = (size_t)b * D2 + n * HD + h;
      k0 = rk[rb]; k1 = rk[rb + 1]; vv0 = rv[rb]; vv1 = rv[rb + 1];
    }
    float p = qv.x * k0 + qv.y * k1;
#pragma unroll
    for (int o = 1; o < 64; o <<= 1) p += __shfl_xor(p, o, 64);
    s[u] = p * SCALE;
    v0[u] = vv0; v1[u] = vv1;
  }
  float m = s[0];
#pragma unroll
  for (int u = 1; u < 5; u++) m = fmaxf(m, s[u]);
  float sum = 0.f, o0 = 0.f, o1 = 0.f;
#pragma unroll
  for (int u = 0; u < 5; u++) {
    float e = expf(s[u] - m);
    sum += e; o0 += e * v0[u]; o1 += e * v1[u];
  }
  *(uint_t*)(att + base) = packbf(o0 / sum, o1 / sum);
}

// ---------------- relay attention phase 1: scores from nodesb/relay vs u; partial wsum of rows
__global__ __launch_bounds__(256) void relay_attn_partial(
    const float* __restrict__ relay, const u16* __restrict__ nodesb,
    const float* __restrict__ u, const float* __restrict__ cvec,
    const int* __restrict__ mask,
    float* __restrict__ pm, float* __restrict__ ps, float* __restrict__ pw) {
  int bn = blockIdx.x;           // b*NH + n
  int b = bn >> 2;
  int c = blockIdx.y;
  int l0 = c * CHUNK;
  int nloc = min(CHUNK, L1 - l0);
  __shared__ float us[D];
  __shared__ float sc[CHUNK];
  __shared__ float red[4];
  __shared__ float accs[2][D];
  int t = threadIdx.x;
  if (t < D) us[t] = u[(size_t)bn * D + t];
  __syncthreads();
  float cb = cvec[bn];
  int wv = t >> 6, lane = t & 63;
  float2 qv = ((const float2*)us)[lane];
  for (int i = wv; i < nloc; i += 4) {
    int p = l0 + i;
    float2 kk;
    if (p == 0) kk = ((const float2*)(relay + (size_t)b * D))[lane];
    else kk = bf2x2(*(const uint_t*)(nodesb + ((size_t)b * L + p - 1) * D + 2 * lane));
    float s = qv.x * kk.x + qv.y * kk.y;
#pragma unroll
    for (int o = 1; o < 64; o <<= 1) s += __shfl_xor(s, o, 64);
    if (lane == 0) {
      s += cb;
      if (p > 0 && mask[b * L + p - 1] == 0) s = -1e30f;
      sc[i] = s;
    }
  }
  __syncthreads();
  float m = -1e30f;
  for (int i = t; i < nloc; i += 256) m = fmaxf(m, sc[i]);
#pragma unroll
  for (int o = 1; o < 64; o <<= 1) m = fmaxf(m, __shfl_xor(m, o, 64));
  if (lane == 0) red[wv] = m;
  __syncthreads();
  m = fmaxf(fmaxf(red[0], red[1]), fmaxf(red[2], red[3]));
  __syncthreads();
  float sum = 0.f;
  for (int i = t; i < nloc; i += 256) { float e = expf(sc[i] - m); sc[i] = e; sum += e; }
#pragma unroll
  for (int o = 1; o < 64; o <<= 1) sum += __shfl_xor(sum, o, 64);
  if (lane == 0) red[wv] = sum;
  __syncthreads();
  sum = red[0] + red[1] + red[2] + red[3];
  int h = t & 127, par = t >> 7;
  float o = 0.f;
  for (int i = par; i < nloc; i += 2) {
    int p = l0 + i;
    float val = (p == 0) ? relay[(size_t)b * D + h]
                         : bf2f(nodesb[((size_t)b * L + p - 1) * D + h]);
    o += sc[i] * val;
  }
  accs[par][h] = o;
  __syncthreads();
  if (t < D) pw[((size_t)bn * NCH + c) * D + t] = accs[0][t] + accs[1][t];
  if (t == 0) { pm[bn * NCH + c] = m; ps[bn * NCH + c] = sum; }
}

// ---------------- combine chunks -> w; satt = w@sv_w^T + sv_b; relay = leaky(satt@so_w^T + so_b)
__global__ __launch_bounds__(256) void relay_final(
    const float* __restrict__ pm, const float* __restrict__ ps, const float* __restrict__ pw,
    const float* __restrict__ svw, const float* __restrict__ svb,
    const float* __restrict__ sow, const float* __restrict__ sob,
    float* __restrict__ out) {
  int b = blockIdx.x, t = threadIdx.x;
  __shared__ float wsum[NH][D];
  __shared__ float satts[D2];
  // stage A: wave n combines chunks for head n
  int n = t >> 6, lane = t & 63;
  {
    int bn = b * NH + n;
    float M = -1e30f;
#pragma unroll
    for (int c = 0; c < NCH; c++) M = fmaxf(M, pm[bn * NCH + c]);
    float S = 0.f;
#pragma unroll
    for (int c = 0; c < NCH; c++) S += ps[bn * NCH + c] * expf(pm[bn * NCH + c] - M);
    float invS = 1.0f / S;
#pragma unroll
    for (int hh = 0; hh < 2; hh++) {
      int h = lane * 2 + hh;
      float o = 0.f;
#pragma unroll
      for (int c = 0; c < NCH; c++)
        o += expf(pm[bn * NCH + c] - M) * pw[((size_t)bn * NCH + c) * D + h];
      wsum[n][h] = o * invS;
    }
  }
  __syncthreads();
  // stage B: satt[nh] = wsum[n]·svw[nh,:] + svb[nh]
#pragma unroll
  for (int rep = 0; rep < 2; rep++) {
    int nh = rep * 256 + t;
    int hn = nh >> 7;
    float acc = svb[nh];
    const float4* wp = (const float4*)(svw + (size_t)nh * D);
    const float4* wl = (const float4*)wsum[hn];
#pragma unroll 8
    for (int d = 0; d < D / 4; d++) {
      float4 a = wl[d], wv4 = wp[d];
      acc += a.x * wv4.x + a.y * wv4.y + a.z * wv4.z + a.w * wv4.w;
    }
    satts[nh] = acc;
  }
  __syncthreads();
  // stage C: out[t] = leaky(satts·sow[t,:] + sob[t]), t<128
  if (t < D) {
    float acc = sob[t];
    const float4* wp = (const float4*)(sow + (size_t)t * D2);
    const float4* a4 = (const float4*)satts;
#pragma unroll 8
    for (int j = 0; j < D2 / 4; j++) {
      float4 a = a4[j], wv4 = wp[j];
      acc += a.x * wv4.x + a.y * wv4.y + a.z * wv4.z + a.w * wv4.w;
    }
    acc = (acc > 0.f) ? acc : 0.01f * acc;
    out[(size_t)b * D + t] = acc;
  }
}

extern "C" void kernel_launch(void* const* d_in, const int* in_sizes, int n_in,
                              void* d_out, int out_size, void* d_ws, size_t ws_size,
                              hipStream_t stream) {
  const int* tokens = (const int*)d_in[0];
  const int* mask = (const int*)d_in[1];
  const float* emb = (const float*)d_in[2];
  const float* proj_w = (const float*)d_in[3];
  const float* proj_b = (const float*)d_in[4];
  const float* ng = (const float*)d_in[5];
  const float* nb = (const float*)d_in[6];
  const float* rq_w = (const float*)d_in[7], * rq_b = (const float*)d_in[8];
  const float* rk_w = (const float*)d_in[9], * rk_b = (const float*)d_in[10];
  const float* rv_w = (const float*)d_in[11], * rv_b = (const float*)d_in[12];
  const float* ro_w = (const float*)d_in[13], * ro_b = (const float*)d_in[14];
  const float* sq_w = (const float*)d_in[15], * sq_b = (const float*)d_in[16];
  const float* sk_w = (const float*)d_in[17], * sk_b = (const float*)d_in[18];
  const float* sv_w = (const float*)d_in[19], * sv_b = (const float*)d_in[20];
  const float* so_w = (const float*)d_in[21], * so_b = (const float*)d_in[22];

  const size_t BLD = (size_t)B * L * D;        // 1,048,576
  const size_t BLD4 = (size_t)B * L * D2;      // 4,194,304
  const size_t WTEN = (size_t)NL * D * D2;     // 196,608 per tensor

  float* fp = (float*)d_ws;
  float* nodes = fp;                    fp += BLD;
  float* relay = fp;                    fp += B * D;
  float* relay_k = fp;                  fp += B * D2;
  float* relay_v = fp;                  fp += B * D2;
  float* uvec = fp;                     fp += B * NH * D;
  float* cvec = fp;                     fp += B * NH;
  float* pm = fp;                       fp += B * NH * NCH;
  float* ps = fp;                       fp += B * NH * NCH;
  float* pw = fp;                       fp += (size_t)B * NH * NCH * D;
  u16* up = (u16*)fp;
  u16* xb = up;                         up += BLD;
  u16* nxb = up;                        up += BLD;
  u16* nodesb = up;                     up += BLD;
  u16* qb = up;                         up += BLD4;
  u16* kb = up;                         up += BLD4;
  u16* vb = up;                         up += BLD4;
  u16* akb = up;                        up += BLD4;
  u16* avb = up;                        up += BLD4;
  u16* attb = up;                       up += BLD4;
  u16* wb = up;                         // 4 * WTEN
  u16* wrq = wb, * wrk = wb + WTEN, * wrv = wb + 2 * WTEN, * wro = wb + 3 * WTEN;

  hipMemsetAsync(relay, 0, B * D * sizeof(float), stream);

  // convert ring-side weights to bf16 (one-time per launch)
  {
    WCArgs wa;
    wa.s[0] = rq_w; wa.s[1] = rk_w; wa.s[2] = rv_w; wa.s[3] = ro_w;
    wa.d[0] = wrq; wa.d[1] = wrk; wa.d[2] = wrv; wa.d[3] = wro;
    wconv<<<dim3(WTEN / 1024, 4), 256, 0, stream>>>(wa);
  }
  // embedding projection: nodes (fp32) + xb (bf16)
  gemm_embed<<<dim3(128, 2), 256, 0, stream>>>(emb, proj_w, proj_b, nodes, xb, tokens, D, E);
  relay_init_kernel<<<B * 64, 128, 0, stream>>>(nodes, relay);

  for (int i = 0; i < NL; i++) {
    const size_t wo = (size_t)i * D * D2;
    const float* rkwi = rk_w + wo, * rkbi = rk_b + (size_t)i * D2;
    const float* rvwi = rv_w + wo, * rvbi = rv_b + (size_t)i * D2;
    const float* rqbi = rq_b + (size_t)i * D2;
    const float* robi = ro_b + (size_t)i * D;
    const float* sqwi = sq_w + wo, * sqbi = sq_b + (size_t)i * D2;
    const float* skwi = sk_w + wo, * skbi = sk_b + (size_t)i * D2;
    const float* svwi = sv_w + wo, * svbi = sv_b + (size_t)i * D2;
    const float* sowi = so_w + wo, * sobi = so_b + (size_t)i * D;

    relay_step<<<B, 256, 0, stream>>>(relay, rkwi, rkbi, rvwi, rvbi, sqwi, sqbi,
                                      skwi, skbi, relay_k, relay_v, uvec, cvec);
    ln_kernel<<<B * L, 128, 0, stream>>>(nodes, nxb, ng + i * D, nb + i * D);

    // fused q,k,v (from nxb) + ak,av (from xb): one dispatch
    {
      GArgs ga = {};
      ga.d[0].A = nxb; ga.d[0].W = wrq + wo; ga.d[0].bias = rqbi; ga.d[0].outb = qb;
      ga.d[1].A = nxb; ga.d[1].W = wrk + wo; ga.d[1].bias = rkbi; ga.d[1].outb = kb;
      ga.d[2].A = nxb; ga.d[2].W = wrv + wo; ga.d[2].bias = rvbi; ga.d[2].outb = vb;
      ga.d[3].A = xb;  ga.d[3].W = wrk + wo; ga.d[3].bias = rkbi; ga.d[3].outb = akb;
      ga.d[4].A = xb;  ga.d[4].W = wrv + wo; ga.d[4].bias = rvbi; ga.d[4].outb = avb;
      gemm_bf<<<dim3(128, 40), 256, 0, stream>>>(ga, 8, D2, D);
    }
    ring_attn_kernel<<<B * L, 256, 0, stream>>>(qb, kb, vb, akb, avb, relay_k, relay_v, attb);
    // nodes = where(pad, 0, nodes + leaky(att @ ro^T + ro_b)); also nodesb (bf16)
    {
      GArgs ga = {};
      ga.d[0].A = attb; ga.d[0].W = wro + wo; ga.d[0].bias = robi;
      ga.d[0].outf = nodes; ga.d[0].resid = nodes; ga.d[0].out2b = nodesb;
      ga.d[0].mask = mask; ga.d[0].residleaky = 1;
      gemm_bf<<<dim3(128, 2), 256, 0, stream>>>(ga, 2, D, D2);
    }
    relay_attn_partial<<<dim3(B * NH, NCH), 256, 0, stream>>>(relay, nodesb, uvec, cvec, mask, pm, ps, pw);
    float* relay_dst = (i == NL - 1) ? (float*)d_out : relay;
    relay_final<<<B, 256, 0, stream>>>(pm, ps, pw, svwi, svbi, sowi, sobi, relay_dst);
  }
}

// Round 8
// 448.945 us; speedup vs baseline: 1.1908x; 1.1908x over previous
//
#include <hip/hip_runtime.h>
#include <hip/hip_bf16.h>

// Problem constants
constexpr int B = 4, L = 2048, E = 300, D = 128, NH = 4, HD = 128, NL = 3, D2 = 512;
constexpr int L1 = L + 1; // 2049
constexpr float EPS = 1e-5f;
constexpr float SCALE = 0.08838834764831843f; // 1/sqrt(128)
constexpr int NCH = 32;              // relay-attention L-chunks
constexpr int CHUNK = 65;            // ceil(2049/32)

typedef unsigned int uint_t;
typedef unsigned short u16;
typedef short bf16x8 __attribute__((ext_vector_type(8)));
typedef float f32x4 __attribute__((ext_vector_type(4)));

__device__ __forceinline__ u16 f2bf(float f) {
  union { float f; uint_t i; } x; x.f = f;
  uint_t r = x.i + 0x7fffu + ((x.i >> 16) & 1u);
  return (u16)(r >> 16);
}
__device__ __forceinline__ uint_t packbf(float a, float b) {
  return (uint_t)f2bf(a) | ((uint_t)f2bf(b) << 16);
}
__device__ __forceinline__ float bf2f(u16 u) {
  union { uint_t i; float f; } x; x.i = ((uint_t)u) << 16; return x.f;
}
__device__ __forceinline__ float2 bf2x2(uint_t u) {
  union { uint_t i; float f; } a, b;
  a.i = (u & 0xffffu) << 16; b.i = u & 0xffff0000u;
  return make_float2(a.f, b.f);
}

// ---------------- weight pre-conversion: 4 tensors (rq,rk,rv,ro), NL*D*D2 fp32 -> bf16
struct WCArgs { const float* s[4]; u16* d[4]; };
__global__ __launch_bounds__(256) void wconv(WCArgs wa) {
  int ti = blockIdx.y;
  const float* s = wa.s[ti]; u16* dd = wa.d[ti];
  int i = (blockIdx.x * 256 + threadIdx.x) * 4;
  float4 f = *(const float4*)(s + i);
  *(uint2*)(dd + i) = make_uint2(packbf(f.x, f.y), packbf(f.z, f.w));
}

// ================= all-bf16 MFMA GEMM, BK=128: out[M,N] = A[M,K] @ W[N,K]^T + bias
// 64x64 tile, 256 threads = 4 waves 2x2 (each 32x32).
struct GDesc {
  const u16* A; const u16* W; const float* bias;
  u16* outb;                // bf16 output (when !residleaky)
  float* outf;              // fp32 output (residleaky path)
  const float* resid; u16* out2b; const int* mask;
  int residleaky;
};
struct GArgs { GDesc d[5]; };

__global__ __launch_bounds__(256) void gemm_bf(GArgs ga, int nby, int N, int K) {
  __shared__ u16 As[64][136];
  __shared__ u16 Ws[64][136];
  int t = threadIdx.x;
  int bm = blockIdx.x;
  int di = blockIdx.y / nby, bn = blockIdx.y - di * nby;
  GDesc d = ga.d[di];
  const int rowA = bm * 64, rowW = bn * 64;

  f32x4 acc[2][2];
#pragma unroll
  for (int i = 0; i < 2; i++)
#pragma unroll
    for (int j = 0; j < 2; j++)
      acc[i][j] = (f32x4){0.f, 0.f, 0.f, 0.f};

  const int r = t >> 2;             // 0..63
  const int c0 = (t & 3) * 32;      // 0,32,64,96 (shorts)
  const int wid = t >> 6;
  const int wm = (wid & 1) * 32, wn = (wid >> 1) * 32;
  const int lr = t & 15, quad = (t >> 4) & 3;

  const u16* Arow = d.A + (size_t)(rowA + r) * K;
  const u16* Wrow = d.W + (size_t)(rowW + r) * K;

  for (int kt = 0; kt < K; kt += 128) {
    uint4 a0 = *(const uint4*)(Arow + kt + c0);
    uint4 a1 = *(const uint4*)(Arow + kt + c0 + 8);
    uint4 a2 = *(const uint4*)(Arow + kt + c0 + 16);
    uint4 a3 = *(const uint4*)(Arow + kt + c0 + 24);
    uint4 w0 = *(const uint4*)(Wrow + kt + c0);
    uint4 w1 = *(const uint4*)(Wrow + kt + c0 + 8);
    uint4 w2 = *(const uint4*)(Wrow + kt + c0 + 16);
    uint4 w3 = *(const uint4*)(Wrow + kt + c0 + 24);
    __syncthreads();
    *(uint4*)&As[r][c0] = a0; *(uint4*)&As[r][c0 + 8] = a1;
    *(uint4*)&As[r][c0 + 16] = a2; *(uint4*)&As[r][c0 + 24] = a3;
    *(uint4*)&Ws[r][c0] = w0; *(uint4*)&Ws[r][c0 + 8] = w1;
    *(uint4*)&Ws[r][c0 + 16] = w2; *(uint4*)&Ws[r][c0 + 24] = w3;
    __syncthreads();
#pragma unroll
    for (int ks = 0; ks < 4; ks++) {
      bf16x8 af[2], bfr[2];
#pragma unroll
      for (int mt = 0; mt < 2; mt++)
        af[mt] = *(const bf16x8*)&As[wm + mt * 16 + lr][ks * 32 + quad * 8];
#pragma unroll
      for (int nt = 0; nt < 2; nt++)
        bfr[nt] = *(const bf16x8*)&Ws[wn + nt * 16 + lr][ks * 32 + quad * 8];
#pragma unroll
      for (int mt = 0; mt < 2; mt++)
#pragma unroll
        for (int nt = 0; nt < 2; nt++)
          acc[mt][nt] = __builtin_amdgcn_mfma_f32_16x16x32_bf16(af[mt], bfr[nt], acc[mt][nt], 0, 0, 0);
    }
  }

  // epilogue: C/D layout col=lane&15, row=quad*4+reg
#pragma unroll
  for (int nt = 0; nt < 2; nt++) {
    int col = rowW + wn + nt * 16 + lr;
    float bv = d.bias[col];
#pragma unroll
    for (int mt = 0; mt < 2; mt++) {
#pragma unroll
      for (int rr = 0; rr < 4; rr++) {
        int row = rowA + wm + mt * 16 + quad * 4 + rr;
        float v = acc[mt][nt][rr] + bv;
        if (d.residleaky) {
          v = (v > 0.f) ? v : 0.01f * v;
          v += d.resid[(size_t)row * N + col];
          if (d.mask[row] == 0) v = 0.f;
          d.outf[(size_t)row * N + col] = v;
          d.out2b[(size_t)row * N + col] = f2bf(v);
        } else {
          d.outb[(size_t)row * N + col] = f2bf(v);
        }
      }
    }
  }
}

// ================= fp32-input MFMA GEMM for the embedding projection (gathered A, K=300)
__global__ __launch_bounds__(256) void gemm_embed(
    const float* __restrict__ A, const float* __restrict__ W, const float* __restrict__ bias,
    float* __restrict__ outf, u16* __restrict__ outb,
    const int* __restrict__ gather, int N, int K) {
  __shared__ u16 As[64][72];
  __shared__ u16 Ws[64][72];
  int t = threadIdx.x;
  int bm = blockIdx.x, bn = blockIdx.y;
  const int rowA = bm * 64, rowW = bn * 64;

  f32x4 acc[2][2];
#pragma unroll
  for (int i = 0; i < 2; i++)
#pragma unroll
    for (int j = 0; j < 2; j++)
      acc[i][j] = (f32x4){0.f, 0.f, 0.f, 0.f};

  const int srow = t >> 2, sc0 = (t & 3) * 16;
  const int wid = t >> 6, wm = (wid & 1) * 32, wn = (wid >> 1) * 32;
  const int lr = t & 15, quad = (t >> 4) & 3;

  const float* Arow = A + (size_t)gather[rowA + srow] * K;
  const float* Wrow = W + (size_t)(rowW + srow) * K;

  for (int kt = 0; kt < K; kt += 64) {
    __syncthreads();
    bool full = (kt + 64 <= K);
#pragma unroll
    for (int ch = 0; ch < 4; ch++) {
      int c = kt + sc0 + ch * 4;
      float4 fa, fw;
      if (full) {
        fa = *(const float4*)(Arow + c);
        fw = *(const float4*)(Wrow + c);
      } else {
        fa.x = (c + 0 < K) ? Arow[c + 0] : 0.f;
        fa.y = (c + 1 < K) ? Arow[c + 1] : 0.f;
        fa.z = (c + 2 < K) ? Arow[c + 2] : 0.f;
        fa.w = (c + 3 < K) ? Arow[c + 3] : 0.f;
        fw.x = (c + 0 < K) ? Wrow[c + 0] : 0.f;
        fw.y = (c + 1 < K) ? Wrow[c + 1] : 0.f;
        fw.z = (c + 2 < K) ? Wrow[c + 2] : 0.f;
        fw.w = (c + 3 < K) ? Wrow[c + 3] : 0.f;
      }
      *(uint2*)&As[srow][sc0 + ch * 4] = make_uint2(packbf(fa.x, fa.y), packbf(fa.z, fa.w));
      *(uint2*)&Ws[srow][sc0 + ch * 4] = make_uint2(packbf(fw.x, fw.y), packbf(fw.z, fw.w));
    }
    __syncthreads();
#pragma unroll
    for (int ks = 0; ks < 2; ks++) {
      bf16x8 af[2], bfr[2];
#pragma unroll
      for (int mt = 0; mt < 2; mt++)
        af[mt] = *(const bf16x8*)&As[wm + mt * 16 + lr][ks * 32 + quad * 8];
#pragma unroll
      for (int nt = 0; nt < 2; nt++)
        bfr[nt] = *(const bf16x8*)&Ws[wn + nt * 16 + lr][ks * 32 + quad * 8];
#pragma unroll
      for (int mt = 0; mt < 2; mt++)
#pragma unroll
        for (int nt = 0; nt < 2; nt++)
          acc[mt][nt] = __builtin_amdgcn_mfma_f32_16x16x32_bf16(af[mt], bfr[nt], acc[mt][nt], 0, 0, 0);
    }
  }
#pragma unroll
  for (int nt = 0; nt < 2; nt++) {
    int col = rowW + wn + nt * 16 + lr;
    float bv = bias[col];
#pragma unroll
    for (int mt = 0; mt < 2; mt++) {
#pragma unroll
      for (int rr = 0; rr < 4; rr++) {
        int row = rowA + wm + mt * 16 + quad * 4 + rr;
        float v = acc[mt][nt][rr] + bv;
        outf[(size_t)row * N + col] = v;       // nodes (fp32)
        outb[(size_t)row * N + col] = f2bf(v); // xb (bf16)
      }
    }
  }
}

// ---------------- relay = mean over L of nodes  (relay zeroed first)
__global__ __launch_bounds__(128) void relay_init_kernel(const float* __restrict__ x, float* __restrict__ relay) {
  int b = blockIdx.x >> 6, c = blockIdx.x & 63, t = threadIdx.x;
  float sum = 0.f;
  for (int i = 0; i < 32; i++) {
    int l = c * 32 + i;
    sum += x[((size_t)b * L + l) * D + t];
  }
  atomicAdd(&relay[b * D + t], sum * (1.0f / L));
}

// ---------------- layernorm (fp32 in, bf16 out)
__global__ __launch_bounds__(128) void ln_kernel(
    const float* __restrict__ in, u16* __restrict__ out,
    const float* __restrict__ g, const float* __restrict__ bb) {
  int row = blockIdx.x, t = threadIdx.x;
  float v = in[(size_t)row * D + t];
  float s = v, s2 = v * v;
#pragma unroll
  for (int o = 1; o < 64; o <<= 1) { s += __shfl_xor(s, o, 64); s2 += __shfl_xor(s2, o, 64); }
  __shared__ float rs[2], rs2[2];
  int w = t >> 6;
  if ((t & 63) == 0) { rs[w] = s; rs2[w] = s2; }
  __syncthreads();
  float S = rs[0] + rs[1], S2 = rs2[0] + rs2[1];
  float mu = S * (1.0f / D);
  float var = S2 * (1.0f / D) - mu * mu;
  float r = rsqrtf(var + EPS);
  out[(size_t)row * D + t] = f2bf((v - mu) * r * g[t] + bb[t]);
}

// ---------------- per-layer relay-side projections, grid (B, 12) x 128 threads:
// chunks 0-3: relay_k = rk_w@relay+b   chunks 4-7: relay_v
// chunks 8-11 (head n): sql = sq proj; u[b,n,:] = SCALE*(sql @ sk_w_n); cvec = SCALE*(sql·skb_n)
__global__ __launch_bounds__(128) void relay_proj(
    const float* __restrict__ relay,
    const float* __restrict__ rkw, const float* __restrict__ rkb,
    const float* __restrict__ rvw, const float* __restrict__ rvb,
    const float* __restrict__ sqw, const float* __restrict__ sqb,
    const float* __restrict__ skw, const float* __restrict__ skb_,
    float* __restrict__ relay_k, float* __restrict__ relay_v,
    float* __restrict__ u, float* __restrict__ cvec) {
  __shared__ float rel[D];
  __shared__ float sql[HD];
  __shared__ float cred[2];
  int b = blockIdx.x, di = blockIdx.y, t = threadIdx.x;
  rel[t] = relay[(size_t)b * D + t];
  __syncthreads();
  const float4* r4 = (const float4*)rel;
  if (di < 8) {
    int which = di >> 2;           // 0 = rk, 1 = rv
    int n = (di & 3) * 128 + t;
    const float* W = which ? rvw : rkw;
    float acc = (which ? rvb : rkb)[n];
    const float4* w4 = (const float4*)(W + (size_t)n * D);
#pragma unroll 8
    for (int i = 0; i < D / 4; i++) {
      float4 w = w4[i], r = r4[i];
      acc += w.x * r.x + w.y * r.y + w.z * r.z + w.w * r.w;
    }
    (which ? relay_v : relay_k)[(size_t)b * D2 + n] = acc;
  } else {
    int n = di - 8;
    // step 1: sql[t] = sq projection (row n*HD+t)
    {
      int nh = n * HD + t;
      float acc = sqb[nh];
      const float4* w4 = (const float4*)(sqw + (size_t)nh * D);
#pragma unroll 8
      for (int i = 0; i < D / 4; i++) {
        float4 w = w4[i], r = r4[i];
        acc += w.x * r.x + w.y * r.y + w.z * r.z + w.w * r.w;
      }
      sql[t] = acc;
    }
    __syncthreads();
    // cvec reduction
    {
      float cp = sql[t] * skb_[n * HD + t];
#pragma unroll
      for (int o = 1; o < 64; o <<= 1) cp += __shfl_xor(cp, o, 64);
      if ((t & 63) == 0) cred[t >> 6] = cp;
    }
    // step 2: u[b,n,t] = SCALE * sum_h sql[h]*skw[(n*HD+h)*D + t]  (coalesced rows, 4-way ILP)
    float a0 = 0.f, a1 = 0.f, a2 = 0.f, a3 = 0.f;
    const float* wp = skw + (size_t)(n * HD) * D + t;
    for (int h = 0; h < HD; h += 4) {
      a0 += sql[h] * wp[(size_t)h * D];
      a1 += sql[h + 1] * wp[(size_t)(h + 1) * D];
      a2 += sql[h + 2] * wp[(size_t)(h + 2) * D];
      a3 += sql[h + 3] * wp[(size_t)(h + 3) * D];
    }
    u[((size_t)b * NH + n) * D + t] = (a0 + a1 + a2 + a3) * SCALE;
    __syncthreads();
    if (t == 0) cvec[b * NH + n] = (cred[0] + cred[1]) * SCALE;
  }
}

// ---------------- ring (windowed) attention; bf16 q/k/v/ak/av + att, fp32 rk/rv
__global__ __launch_bounds__(256) void ring_attn_kernel(
    const u16* __restrict__ q, const u16* __restrict__ k, const u16* __restrict__ v,
    const u16* __restrict__ akr, const u16* __restrict__ avr,
    const float* __restrict__ rk, const float* __restrict__ rv,
    u16* __restrict__ att) {
  int bl = blockIdx.x;
  int b = bl >> 11, l = bl & (L - 1);
  int n = threadIdx.x >> 6, lane = threadIdx.x & 63;
  int h = lane << 1;
  size_t base = (size_t)bl * D2 + n * HD + h;
  float2 qv = bf2x2(*(const uint_t*)(q + base));
  float s[5], v0[5], v1[5];
#pragma unroll
  for (int u = 0; u < 5; u++) {
    float k0 = 0.f, k1 = 0.f, vv0 = 0.f, vv1 = 0.f;
    if (u < 3) {
      int ll = l + u - 1;
      if (ll >= 0 && ll < L) {
        size_t off = ((size_t)b * L + ll) * D2 + n * HD + h;
        float2 kf = bf2x2(*(const uint_t*)(k + off));
        float2 vf = bf2x2(*(const uint_t*)(v + off));
        k0 = kf.x; k1 = kf.y; vv0 = vf.x; vv1 = vf.y;
      }
    } else if (u == 3) {
      float2 kf = bf2x2(*(const uint_t*)(akr + base));
      float2 vf = bf2x2(*(const uint_t*)(avr + base));
      k0 = kf.x; k1 = kf.y; vv0 = vf.x; vv1 = vf.y;
    } else {
      size_t rb = (size_t)b * D2 + n * HD + h;
      k0 = rk[rb]; k1 = rk[rb + 1]; vv0 = rv[rb]; vv1 = rv[rb + 1];
    }
    float p = qv.x * k0 + qv.y * k1;
#pragma unroll
    for (int o = 1; o < 64; o <<= 1) p += __shfl_xor(p, o, 64);
    s[u] = p * SCALE;
    v0[u] = vv0; v1[u] = vv1;
  }
  float m = s[0];
#pragma unroll
  for (int u = 1; u < 5; u++) m = fmaxf(m, s[u]);
  float sum = 0.f, o0 = 0.f, o1 = 0.f;
#pragma unroll
  for (int u = 0; u < 5; u++) {
    float e = expf(s[u] - m);
    sum += e; o0 += e * v0[u]; o1 += e * v1[u];
  }
  *(uint_t*)(att + base) = packbf(o0 / sum, o1 / sum);
}

// ---------------- relay attention phase 1: scores from nodesb/relay vs u; partial wsum of rows
__global__ __launch_bounds__(256) void relay_attn_partial(
    const float* __restrict__ relay, const u16* __restrict__ nodesb,
    const float* __restrict__ u, const float* __restrict__ cvec,
    const int* __restrict__ mask,
    float* __restrict__ pm, float* __restrict__ ps, float* __restrict__ pw) {
  int bn = blockIdx.x;           // b*NH + n
  int b = bn >> 2;
  int c = blockIdx.y;
  int l0 = c * CHUNK;
  int nloc = min(CHUNK, L1 - l0);
  __shared__ float us[D];
  __shared__ float sc[CHUNK];
  __shared__ float red[4];
  __shared__ float accs[2][D];
  int t = threadIdx.x;
  if (t < D) us[t] = u[(size_t)bn * D + t];
  __syncthreads();
  float cb = cvec[bn];
  int wv = t >> 6, lane = t & 63;
  float2 qv = ((const float2*)us)[lane];
  for (int i = wv; i < nloc; i += 4) {
    int p = l0 + i;
    float2 kk;
    if (p == 0) kk = ((const float2*)(relay + (size_t)b * D))[lane];
    else kk = bf2x2(*(const uint_t*)(nodesb + ((size_t)b * L + p - 1) * D + 2 * lane));
    float s = qv.x * kk.x + qv.y * kk.y;
#pragma unroll
    for (int o = 1; o < 64; o <<= 1) s += __shfl_xor(s, o, 64);
    if (lane == 0) {
      s += cb;
      if (p > 0 && mask[b * L + p - 1] == 0) s = -1e30f;
      sc[i] = s;
    }
  }
  __syncthreads();
  float m = -1e30f;
  for (int i = t; i < nloc; i += 256) m = fmaxf(m, sc[i]);
#pragma unroll
  for (int o = 1; o < 64; o <<= 1) m = fmaxf(m, __shfl_xor(m, o, 64));
  if (lane == 0) red[wv] = m;
  __syncthreads();
  m = fmaxf(fmaxf(red[0], red[1]), fmaxf(red[2], red[3]));
  __syncthreads();
  float sum = 0.f;
  for (int i = t; i < nloc; i += 256) { float e = expf(sc[i] - m); sc[i] = e; sum += e; }
#pragma unroll
  for (int o = 1; o < 64; o <<= 1) sum += __shfl_xor(sum, o, 64);
  if (lane == 0) red[wv] = sum;
  __syncthreads();
  sum = red[0] + red[1] + red[2] + red[3];
  int h = t & 127, par = t >> 7;
  float o = 0.f;
  for (int i = par; i < nloc; i += 2) {
    int p = l0 + i;
    float val = (p == 0) ? relay[(size_t)b * D + h]
                         : bf2f(nodesb[((size_t)b * L + p - 1) * D + h]);
    o += sc[i] * val;
  }
  accs[par][h] = o;
  __syncthreads();
  if (t < D) pw[((size_t)bn * NCH + c) * D + t] = accs[0][t] + accs[1][t];
  if (t == 0) { pm[bn * NCH + c] = m; ps[bn * NCH + c] = sum; }
}

// ---------------- combine chunks -> w; satt = w@sv_w^T + sv_b; relay = leaky(satt@so_w^T + so_b)
__global__ __launch_bounds__(256) void relay_final(
    const float* __restrict__ pm, const float* __restrict__ ps, const float* __restrict__ pw,
    const float* __restrict__ svw, const float* __restrict__ svb,
    const float* __restrict__ sow, const float* __restrict__ sob,
    float* __restrict__ out) {
  int b = blockIdx.x, t = threadIdx.x;
  __shared__ float wsum[NH][D];
  __shared__ float satts[D2];
  // stage A: wave n combines chunks for head n
  int n = t >> 6, lane = t & 63;
  {
    int bn = b * NH + n;
    float M = -1e30f;
#pragma unroll
    for (int c = 0; c < NCH; c++) M = fmaxf(M, pm[bn * NCH + c]);
    float S = 0.f;
#pragma unroll
    for (int c = 0; c < NCH; c++) S += ps[bn * NCH + c] * expf(pm[bn * NCH + c] - M);
    float invS = 1.0f / S;
#pragma unroll
    for (int hh = 0; hh < 2; hh++) {
      int h = lane * 2 + hh;
      float o = 0.f;
#pragma unroll
      for (int c = 0; c < NCH; c++)
        o += expf(pm[bn * NCH + c] - M) * pw[((size_t)bn * NCH + c) * D + h];
      wsum[n][h] = o * invS;
    }
  }
  __syncthreads();
  // stage B: satt[nh] = wsum[n]·svw[nh,:] + svb[nh]
#pragma unroll
  for (int rep = 0; rep < 2; rep++) {
    int nh = rep * 256 + t;
    int hn = nh >> 7;
    float acc = svb[nh];
    const float4* wp = (const float4*)(svw + (size_t)nh * D);
    const float4* wl = (const float4*)wsum[hn];
#pragma unroll 8
    for (int d = 0; d < D / 4; d++) {
      float4 a = wl[d], wv4 = wp[d];
      acc += a.x * wv4.x + a.y * wv4.y + a.z * wv4.z + a.w * wv4.w;
    }
    satts[nh] = acc;
  }
  __syncthreads();
  // stage C: out[t] = leaky(satts·sow[t,:] + sob[t]), t<128
  if (t < D) {
    float acc = sob[t];
    const float4* wp = (const float4*)(sow + (size_t)t * D2);
    const float4* a4 = (const float4*)satts;
#pragma unroll 8
    for (int j = 0; j < D2 / 4; j++) {
      float4 a = a4[j], wv4 = wp[j];
      acc += a.x * wv4.x + a.y * wv4.y + a.z * wv4.z + a.w * wv4.w;
    }
    acc = (acc > 0.f) ? acc : 0.01f * acc;
    out[(size_t)b * D + t] = acc;
  }
}

extern "C" void kernel_launch(void* const* d_in, const int* in_sizes, int n_in,
                              void* d_out, int out_size, void* d_ws, size_t ws_size,
                              hipStream_t stream) {
  const int* tokens = (const int*)d_in[0];
  const int* mask = (const int*)d_in[1];
  const float* emb = (const float*)d_in[2];
  const float* proj_w = (const float*)d_in[3];
  const float* proj_b = (const float*)d_in[4];
  const float* ng = (const float*)d_in[5];
  const float* nb = (const float*)d_in[6];
  const float* rq_w = (const float*)d_in[7], * rq_b = (const float*)d_in[8];
  const float* rk_w = (const float*)d_in[9], * rk_b = (const float*)d_in[10];
  const float* rv_w = (const float*)d_in[11], * rv_b = (const float*)d_in[12];
  const float* ro_w = (const float*)d_in[13], * ro_b = (const float*)d_in[14];
  const float* sq_w = (const float*)d_in[15], * sq_b = (const float*)d_in[16];
  const float* sk_w = (const float*)d_in[17], * sk_b = (const float*)d_in[18];
  const float* sv_w = (const float*)d_in[19], * sv_b = (const float*)d_in[20];
  const float* so_w = (const float*)d_in[21], * so_b = (const float*)d_in[22];

  const size_t BLD = (size_t)B * L * D;        // 1,048,576
  const size_t BLD4 = (size_t)B * L * D2;      // 4,194,304
  const size_t WTEN = (size_t)NL * D * D2;     // 196,608 per tensor

  float* fp = (float*)d_ws;
  float* nodes = fp;                    fp += BLD;
  float* relay = fp;                    fp += B * D;
  float* relay_k = fp;                  fp += B * D2;
  float* relay_v = fp;                  fp += B * D2;
  float* uvec = fp;                     fp += B * NH * D;
  float* cvec = fp;                     fp += B * NH;
  float* pm = fp;                       fp += B * NH * NCH;
  float* ps = fp;                       fp += B * NH * NCH;
  float* pw = fp;                       fp += (size_t)B * NH * NCH * D;
  u16* up = (u16*)fp;
  u16* xb = up;                         up += BLD;
  u16* nxb = up;                        up += BLD;
  u16* nodesb = up;                     up += BLD;
  u16* qb = up;                         up += BLD4;
  u16* kb = up;                         up += BLD4;
  u16* vb = up;                         up += BLD4;
  u16* akb = up;                        up += BLD4;
  u16* avb = up;                        up += BLD4;
  u16* attb = up;                       up += BLD4;
  u16* wb = up;                         // 4 * WTEN
  u16* wrq = wb, * wrk = wb + WTEN, * wrv = wb + 2 * WTEN, * wro = wb + 3 * WTEN;

  hipMemsetAsync(relay, 0, B * D * sizeof(float), stream);

  // convert ring-side weights to bf16 (one-time per launch)
  {
    WCArgs wa;
    wa.s[0] = rq_w; wa.s[1] = rk_w; wa.s[2] = rv_w; wa.s[3] = ro_w;
    wa.d[0] = wrq; wa.d[1] = wrk; wa.d[2] = wrv; wa.d[3] = wro;
    wconv<<<dim3(WTEN / 1024, 4), 256, 0, stream>>>(wa);
  }
  // embedding projection: nodes (fp32) + xb (bf16)
  gemm_embed<<<dim3(128, 2), 256, 0, stream>>>(emb, proj_w, proj_b, nodes, xb, tokens, D, E);
  relay_init_kernel<<<B * 64, 128, 0, stream>>>(nodes, relay);

  for (int i = 0; i < NL; i++) {
    const size_t wo = (size_t)i * D * D2;
    const float* rkwi = rk_w + wo, * rkbi = rk_b + (size_t)i * D2;
    const float* rvwi = rv_w + wo, * rvbi = rv_b + (size_t)i * D2;
    const float* rqbi = rq_b + (size_t)i * D2;
    const float* robi = ro_b + (size_t)i * D;
    const float* sqwi = sq_w + wo, * sqbi = sq_b + (size_t)i * D2;
    const float* skwi = sk_w + wo, * skbi = sk_b + (size_t)i * D2;
    const float* svwi = sv_w + wo, * svbi = sv_b + (size_t)i * D2;
    const float* sowi = so_w + wo, * sobi = so_b + (size_t)i * D;

    relay_proj<<<dim3(B, 12), 128, 0, stream>>>(relay, rkwi, rkbi, rvwi, rvbi, sqwi, sqbi,
                                                skwi, skbi, relay_k, relay_v, uvec, cvec);
    ln_kernel<<<B * L, 128, 0, stream>>>(nodes, nxb, ng + i * D, nb + i * D);

    // fused q,k,v (from nxb) + ak,av (from xb): one dispatch
    {
      GArgs ga = {};
      ga.d[0].A = nxb; ga.d[0].W = wrq + wo; ga.d[0].bias = rqbi; ga.d[0].outb = qb;
      ga.d[1].A = nxb; ga.d[1].W = wrk + wo; ga.d[1].bias = rkbi; ga.d[1].outb = kb;
      ga.d[2].A = nxb; ga.d[2].W = wrv + wo; ga.d[2].bias = rvbi; ga.d[2].outb = vb;
      ga.d[3].A = xb;  ga.d[3].W = wrk + wo; ga.d[3].bias = rkbi; ga.d[3].outb = akb;
      ga.d[4].A = xb;  ga.d[4].W = wrv + wo; ga.d[4].bias = rvbi; ga.d[4].outb = avb;
      gemm_bf<<<dim3(128, 40), 256, 0, stream>>>(ga, 8, D2, D);
    }
    ring_attn_kernel<<<B * L, 256, 0, stream>>>(qb, kb, vb, akb, avb, relay_k, relay_v, attb);
    // nodes = where(pad, 0, nodes + leaky(att @ ro^T + ro_b)); also nodesb (bf16)
    {
      GArgs ga = {};
      ga.d[0].A = attb; ga.d[0].W = wro + wo; ga.d[0].bias = robi;
      ga.d[0].outf = nodes; ga.d[0].resid = nodes; ga.d[0].out2b = nodesb;
      ga.d[0].mask = mask; ga.d[0].residleaky = 1;
      gemm_bf<<<dim3(128, 2), 256, 0, stream>>>(ga, 2, D, D2);
    }
    relay_attn_partial<<<dim3(B * NH, NCH), 256, 0, stream>>>(relay, nodesb, uvec, cvec, mask, pm, ps, pw);
    float* relay_dst = (i == NL - 1) ? (float*)d_out : relay;
    relay_final<<<B, 256, 0, stream>>>(pm, ps, pw, svwi, svbi, sowi, sobi, relay_dst);
  }
}